// Round 6
// baseline (63.459 us; speedup 1.0000x reference)
//
#include <hip/hip_runtime.h>
#include <math.h>
#include <stdint.h>

// GaussianMultiScore: B=524288 independent D=8 Gaussian-product scores.
// R1: per-thread float4 gather: 817MB fetch, 245us.
// R3: LDS-staged cho (16KB, 1-wave blocks, 2 drains/tile): 52us, 6.4 waves/CU.
// R4: 32KB dbuf, 1 drain: 59us, 5 waves/CU.
// R5: 36KB persistent counted-vmcnt pipeline: 62us, 4 waves/CU.
//   => perf tracks RESIDENT WAVES, not pipeline cleverness. LDS is the cap.
// R6: minimum footprint (single 16KB cho buffer, mu via registers) +
//     PERSISTENT grid of exactly 10 blocks/CU so the static 10-wave limit
//     is actually resident (R3 only averaged 6.4 due to block churn).
//
// Math (one Cholesky total): lam_new = cho0+cho1 = M.
//  Mt = J*M*J = Gt*Gt^T;  diag(chol(inv(M))) = reversed 1/diag(Gt)
//  sum(log diag_new^2) = -logdet(M);  mu_new via two triangular solves;
//  diff^T M diff = ||Gt^T (J diff)||^2;  det_sum(faithful) = sum 1/gt_ii^2.

constexpr float LOG_2PI_F = 1.8378770664093453f;
constexpr double TWO_PI_D = 6.283185307179586476925286766559;
constexpr float POW8_2PI =
    (float)(TWO_PI_D*TWO_PI_D*TWO_PI_D*TWO_PI_D*TWO_PI_D*TWO_PI_D*TWO_PI_D*TWO_PI_D);

#define TRI(i) (((i)*((i)+1))/2)

typedef __attribute__((address_space(1))) const uint32_t glb_u32_t;
typedef __attribute__((address_space(3))) uint32_t       lds_u32_t;

// 16 gload_lds: 64 elements x 256B of cho, XOR-swizzled via the SOURCE addr
// (global_load_lds writes linearly, base + lane*16).
__device__ __forceinline__ void stage_cho(const float* __restrict__ choP,
                                          size_t blockBase, int B,
                                          float* buf, int t)
{
#pragma unroll
    for (int i = 0; i < 16; ++i) {
        int g  = i * 64 + t;        // linear f4 slot in the 1024-f4 tile
        int r  = g >> 4;            // local element 0..63
        int s4 = g & 15;            // f4 slot within element
        int j  = s4 ^ (r & 15);     // logical f4 index whose data lands here
        size_t e = blockBase + (size_t)r;
        if (e >= (size_t)B) e = (size_t)B - 1;
        __builtin_amdgcn_global_load_lds(
            (glb_u32_t*)(const void*)(choP + e * 64 + (size_t)(j * 4)),
            (lds_u32_t*)(void*)(buf + g * 4),
            16, 0, 0);
    }
}

#define WAIT_ALL() asm volatile("s_waitcnt vmcnt(0) lgkmcnt(0)" ::: "memory")

template <bool FIRST>
__device__ __forceinline__ void pass_lds(
    const float* cbuf, int t, const float mu[8],
    float mt[36], float eta[8], float& quad_out, float& prod_out)
{
    const float4* L4 = reinterpret_cast<const float4*>(cbuf);
    const int base = t * 16;
    const int sw   = t & 15;
    float quad = 0.0f, prod = 1.0f;
#pragma unroll
    for (int r = 0; r < 8; ++r) {
        float4 lo = L4[base + ((2 * r)     ^ sw)];
        float4 hi = L4[base + ((2 * r + 1) ^ sw)];
        float row[8] = {lo.x, lo.y, lo.z, lo.w, hi.x, hi.y, hi.z, hi.w};
        float e = 0.0f;
#pragma unroll
        for (int j = 0; j < 8; ++j) e = fmaf(row[j], mu[j], e);
        if (FIRST) eta[r] = e; else eta[r] += e;
        quad = fmaf(mu[r], e, quad);
        prod *= row[r];
        // reversed lower triangle: Mt[i][j] = M[7-i][7-j], keep j<=i (c>=r)
#pragma unroll
        for (int c = r; c < 8; ++c) {
            int i = 7 - r, jj = 7 - c;
            if (FIRST) mt[TRI(i) + jj]  = row[c];
            else       mt[TRI(i) + jj] += row[c];
        }
    }
    quad_out = quad;
    prod_out = prod;
}

__global__ __launch_bounds__(64) void gms_kernel(
    const float* __restrict__ mu0, const float* __restrict__ mu1,
    const float* __restrict__ cho0, const float* __restrict__ cho1,
    const float* __restrict__ sample, float* __restrict__ out, int B)
{
    __shared__ float lds[64 * 64];   // 16KB -> 10 single-wave blocks/CU
    const int t = threadIdx.x;
    const int nTiles = B >> 6;

    float s[8];
    {
        float4 v0 = reinterpret_cast<const float4*>(sample)[0];
        float4 v1 = reinterpret_cast<const float4*>(sample)[1];
        s[0]=v0.x; s[1]=v0.y; s[2]=v0.z; s[3]=v0.w;
        s[4]=v1.x; s[5]=v1.y; s[6]=v1.z; s[7]=v1.w;
    }

    for (int tile = blockIdx.x; tile < nTiles; tile += gridDim.x) {
        const size_t blockBase = (size_t)tile * 64;
        const size_t bb = blockBase + (size_t)t;
        const size_t be = bb < (size_t)B ? bb : (size_t)B - 1;

        stage_cho(cho0, blockBase, B, lds, t);

        float mA[8], mB[8];
        {
            const float4* m4 = reinterpret_cast<const float4*>(mu0 + be * 8);
            float4 a = m4[0], c = m4[1];
            mA[0]=a.x; mA[1]=a.y; mA[2]=a.z; mA[3]=a.w;
            mA[4]=c.x; mA[5]=c.y; mA[6]=c.z; mA[7]=c.w;
        }
        {
            const float4* m4 = reinterpret_cast<const float4*>(mu1 + be * 8);
            float4 a = m4[0], c = m4[1];
            mB[0]=a.x; mB[1]=a.y; mB[2]=a.z; mB[3]=a.w;
            mB[4]=c.x; mB[5]=c.y; mB[6]=c.z; mB[7]=c.w;
        }

        WAIT_ALL();                 // cho0 tile resident (single-wave block)

        float mt[36], eta[8];
        float quad0, quad1, p0, p1;
        pass_lds<true>(lds, t, mA, mt, eta, quad0, p0);

        asm volatile("s_waitcnt lgkmcnt(0)" ::: "memory");  // reads done
        stage_cho(cho1, blockBase, B, lds, t);
        WAIT_ALL();                 // cho1 tile resident

        pass_lds<false>(lds, t, mB, mt, eta, quad1, p1);

        // ---- Cholesky of mt in place (D=8, fully unrolled) ----
        float ginv[8];
        float gprod = 1.0f;
#pragma unroll
        for (int j = 0; j < 8; ++j) {
            float d = mt[TRI(j) + j];
#pragma unroll
            for (int k = 0; k < j; ++k) {
                float v = mt[TRI(j) + k];
                d = fmaf(-v, v, d);
            }
            float sq = sqrtf(d);
            mt[TRI(j) + j] = sq;
            gprod *= sq;
            float inv = 1.0f / sq;
            ginv[j] = inv;
#pragma unroll
            for (int i = j + 1; i < 8; ++i) {
                float v = mt[TRI(i) + j];
#pragma unroll
                for (int k = 0; k < j; ++k)
                    v = fmaf(-mt[TRI(i) + k], mt[TRI(j) + k], v);
                mt[TRI(i) + j] = v * inv;
            }
        }
        float logdetM = __logf(gprod * gprod);

        // ---- solve Mt * xt = reversed(eta) ----
        float er[8];
#pragma unroll
        for (int i = 0; i < 8; ++i) er[i] = eta[7 - i];
        float y[8];
#pragma unroll
        for (int i = 0; i < 8; ++i) {
            float v = er[i];
#pragma unroll
            for (int k = 0; k < i; ++k) v = fmaf(-mt[TRI(i) + k], y[k], v);
            y[i] = v * ginv[i];
        }
        float x[8];
#pragma unroll
        for (int ii = 7; ii >= 0; --ii) {
            float v = y[ii];
#pragma unroll
            for (int k = ii + 1; k < 8; ++k) v = fmaf(-mt[TRI(k) + ii], x[k], v);
            x[ii] = v * ginv[ii];
        }

        float qn = 0.0f;
#pragma unroll
        for (int i = 0; i < 8; ++i) qn = fmaf(x[i], er[i], qn);

        float dd[8];
#pragma unroll
        for (int i = 0; i < 8; ++i) dd[i] = x[i] - s[7 - i];
        float ep = 0.0f;
#pragma unroll
        for (int i = 0; i < 8; ++i) {
            float z = 0.0f;
#pragma unroll
            for (int k = i; k < 8; ++k) z = fmaf(mt[TRI(k) + i], dd[k], z);
            ep = fmaf(z, z, ep);
        }
        float exp_part = -0.5f * ep;

        float det_sum = 0.0f;
#pragma unroll
        for (int i = 0; i < 8; ++i) det_sum = fmaf(ginv[i], ginv[i], det_sum);

        float sumlog0 = __logf(p0 * p0);
        float sumlog1 = __logf(p1 * p1);
        float zeta0   = -0.5f * (8.0f * LOG_2PI_F - sumlog0 + quad0);
        float zeta1   = -0.5f * (8.0f * LOG_2PI_F - sumlog1 + quad1);
        float zeta_n  = -0.5f * (8.0f * LOG_2PI_F + logdetM + qn);
        float scale   = zeta0 + zeta1 - zeta_n;

        float result = __expf(scale + exp_part) / sqrtf(POW8_2PI * det_sum);
        if (bb < (size_t)B) out[bb] = result;
    }
}

extern "C" void kernel_launch(void* const* d_in, const int* in_sizes, int n_in,
                              void* d_out, int out_size, void* d_ws, size_t ws_size,
                              hipStream_t stream) {
    const float* mu0    = (const float*)d_in[0];
    const float* mu1    = (const float*)d_in[1];
    const float* cho0   = (const float*)d_in[2];
    const float* cho1   = (const float*)d_in[3];
    const float* sample = (const float*)d_in[4];
    float* out = (float*)d_out;
    int B = in_sizes[0] / 8;
    int nTiles = (B + 63) / 64;
    int blocks = 256 * 10;                  // exactly 10 single-wave blocks/CU (16KB LDS each)
    if (blocks > nTiles) blocks = nTiles;
    gms_kernel<<<dim3(blocks), dim3(64), 0, stream>>>(
        mu0, mu1, cho0, cho1, sample, out, B);
}

// Round 7
// 51.532 us; speedup vs baseline: 1.2315x; 1.2315x over previous
//
#include <hip/hip_runtime.h>
#include <math.h>
#include <stdint.h>

// GaussianMultiScore: B=524288 independent D=8 Gaussian-product scores.
// Input 302MB (cho 268 + mu 34), output 2MB. One thread per element,
// D=8 linear algebra fully unrolled in registers; cho staged via LDS.
//
// Optimization history (measured on MI355X):
// R1: per-thread float4 gather: 817MB HBM fetch (2.7x overfetch), 245us.
// R3: LDS-staged cho (global_load_lds 16B, XOR-swizzled source, 16KB/block,
//     one-wave blocks, 2 barrier drains/tile): 52.1us. FETCH=147MB (L3
//     serves the rest). Total delivery 302MB/52.1us = 5.84 TB/s = 93% of
//     the m13 float4-copy ceiling (6.29 TB/s). <- BEST
// R4: 32KB double-buffer, 1 drain: 58.9us (waves/CU 10->5).
// R5: 36KB persistent counted-vmcnt(18) pipeline: 61.6us (4 waves/CU).
// R6: 16KB persistent grid: 63.5us (VGPR 92->144, occupancy 9.8%).
//   => R4-R6 falsify the latency/occupancy/pipelining theories. The kernel
//      is DELIVERY-BANDWIDTH-bound (~5.8-5.9 TB/s shared HBM+L3 path).
//      Byte reduction impossible: the needed triangle of each 256B matrix
//      touches all four 64B lines, so line-granular traffic is fixed.
//      No inter-block reuse -> XCD swizzle has no mechanism. This revert
//      to R3 is the roofline kernel.
//
// Math (one Cholesky total): lam_new = cho0+cho1 = M.
//  Mt = J*M*J = Gt*Gt^T;  diag(chol(inv(M))) = reversed 1/diag(Gt)
//  sum(log diag_new^2) = -logdet(M);  mu_new via two triangular solves;
//  diff^T M diff = ||Gt^T (J diff)||^2;  det_sum(faithful) = sum 1/gt_ii^2.

constexpr float LOG_2PI_F = 1.8378770664093453f;
constexpr double TWO_PI_D = 6.283185307179586476925286766559;
constexpr float POW8_2PI =
    (float)(TWO_PI_D*TWO_PI_D*TWO_PI_D*TWO_PI_D*TWO_PI_D*TWO_PI_D*TWO_PI_D*TWO_PI_D);

#define TRI(i) (((i)*((i)+1))/2)

typedef __attribute__((address_space(1))) const uint32_t glb_u32_t;
typedef __attribute__((address_space(3))) uint32_t       lds_u32_t;

// Stage 64 elements x 256B of cho into lds, swizzled so that the reader's
// slot (j ^ (elem&15)) holds logical float4 j. global_load_lds writes
// linearly (base + lane*16), so the swizzle is applied to the SOURCE address.
// choP is the UNOFFSET array base; element index e = blockBase + r.
__device__ __forceinline__ void stage_cho(const float* __restrict__ choP,
                                          size_t blockBase, int B,
                                          float* lds, int t)
{
#pragma unroll
    for (int i = 0; i < 16; ++i) {
        int g  = i * 64 + t;        // linear f4 slot in the 1024-f4 tile
        int r  = g >> 4;            // local element 0..63
        int s4 = g & 15;            // f4 slot within element
        int j  = s4 ^ (r & 15);     // logical f4 index whose data lands here
        size_t e = blockBase + (size_t)r;
        if (e >= (size_t)B) e = (size_t)B - 1;   // clamp (B%64==0 normally)
        __builtin_amdgcn_global_load_lds(
            (glb_u32_t*)(const void*)(choP + e * 64 + (size_t)(j * 4)),
            (lds_u32_t*)(void*)(lds + g * 4),
            16, 0, 0);
    }
}

template <bool FIRST>
__device__ __forceinline__ void pass_lds(
    const float* lds, int t, const float mu[8],
    float mt[36], float eta[8], float& quad_out, float& prod_out)
{
    const float4* L4 = reinterpret_cast<const float4*>(lds);
    const int base = t * 16;
    const int sw   = t & 15;
    float quad = 0.0f, prod = 1.0f;
#pragma unroll
    for (int r = 0; r < 8; ++r) {
        float4 lo = L4[base + ((2 * r)     ^ sw)];
        float4 hi = L4[base + ((2 * r + 1) ^ sw)];
        float row[8] = {lo.x, lo.y, lo.z, lo.w, hi.x, hi.y, hi.z, hi.w};
        float e = 0.0f;
#pragma unroll
        for (int j = 0; j < 8; ++j) e = fmaf(row[j], mu[j], e);
        if (FIRST) eta[r] = e; else eta[r] += e;
        quad = fmaf(mu[r], e, quad);
        prod *= row[r];
        // reversed lower triangle: Mt[i][j] = M[7-i][7-j], keep j<=i (c>=r)
#pragma unroll
        for (int c = r; c < 8; ++c) {
            int i = 7 - r, jj = 7 - c;
            if (FIRST) mt[TRI(i) + jj]  = row[c];
            else       mt[TRI(i) + jj] += row[c];
        }
    }
    quad_out = quad;
    prod_out = prod;
}

__global__ __launch_bounds__(64) void gms_kernel(
    const float* __restrict__ mu0, const float* __restrict__ mu1,
    const float* __restrict__ cho0, const float* __restrict__ cho1,
    const float* __restrict__ sample, float* __restrict__ out, int B)
{
    __shared__ float lds[64 * 64];   // 16KB -> 10 blocks/CU static
    const int t = threadIdx.x;
    const size_t blockBase = (size_t)blockIdx.x * 64;
    const size_t bb = blockBase + (size_t)t;
    const size_t be = bb < (size_t)B ? bb : (size_t)B - 1;

    stage_cho(cho0, blockBase, B, lds, t);

    float mA[8], mB[8], s[8];
    {
        const float4* m4 = reinterpret_cast<const float4*>(mu0 + be * 8);
        float4 a = m4[0], c = m4[1];
        mA[0]=a.x; mA[1]=a.y; mA[2]=a.z; mA[3]=a.w;
        mA[4]=c.x; mA[5]=c.y; mA[6]=c.z; mA[7]=c.w;
    }
    {
        const float4* m4 = reinterpret_cast<const float4*>(mu1 + be * 8);
        float4 a = m4[0], c = m4[1];
        mB[0]=a.x; mB[1]=a.y; mB[2]=a.z; mB[3]=a.w;
        mB[4]=c.x; mB[5]=c.y; mB[6]=c.z; mB[7]=c.w;
    }
    {
        float4 v0 = reinterpret_cast<const float4*>(sample)[0];
        float4 v1 = reinterpret_cast<const float4*>(sample)[1];
        s[0]=v0.x; s[1]=v0.y; s[2]=v0.z; s[3]=v0.w;
        s[4]=v1.x; s[5]=v1.y; s[6]=v1.z; s[7]=v1.w;
    }

    __syncthreads();                 // vmcnt drain: cho0 tile resident

    float mt[36], eta[8];
    float quad0, quad1, p0, p1;
    pass_lds<true>(lds, t, mA, mt, eta, quad0, p0);

    __syncthreads();                 // all reads of buffer done
    stage_cho(cho1, blockBase, B, lds, t);
    __syncthreads();                 // cho1 tile resident

    pass_lds<false>(lds, t, mB, mt, eta, quad1, p1);

    // ---- Cholesky of mt in place (D=8, fully unrolled) ----
    float ginv[8];
    float gprod = 1.0f;
#pragma unroll
    for (int j = 0; j < 8; ++j) {
        float d = mt[TRI(j) + j];
#pragma unroll
        for (int k = 0; k < j; ++k) {
            float v = mt[TRI(j) + k];
            d = fmaf(-v, v, d);
        }
        float sq = sqrtf(d);
        mt[TRI(j) + j] = sq;
        gprod *= sq;
        float inv = 1.0f / sq;
        ginv[j] = inv;
#pragma unroll
        for (int i = j + 1; i < 8; ++i) {
            float v = mt[TRI(i) + j];
#pragma unroll
            for (int k = 0; k < j; ++k)
                v = fmaf(-mt[TRI(i) + k], mt[TRI(j) + k], v);
            mt[TRI(i) + j] = v * inv;
        }
    }
    float logdetM = __logf(gprod * gprod);

    // ---- solve Mt * xt = reversed(eta) ----
    float er[8];
#pragma unroll
    for (int i = 0; i < 8; ++i) er[i] = eta[7 - i];
    float y[8];
#pragma unroll
    for (int i = 0; i < 8; ++i) {
        float v = er[i];
#pragma unroll
        for (int k = 0; k < i; ++k) v = fmaf(-mt[TRI(i) + k], y[k], v);
        y[i] = v * ginv[i];
    }
    float x[8];
#pragma unroll
    for (int ii = 7; ii >= 0; --ii) {
        float v = y[ii];
#pragma unroll
        for (int k = ii + 1; k < 8; ++k) v = fmaf(-mt[TRI(k) + ii], x[k], v);
        x[ii] = v * ginv[ii];
    }

    float qn = 0.0f;
#pragma unroll
    for (int i = 0; i < 8; ++i) qn = fmaf(x[i], er[i], qn);

    float dd[8];
#pragma unroll
    for (int i = 0; i < 8; ++i) dd[i] = x[i] - s[7 - i];
    float ep = 0.0f;
#pragma unroll
    for (int i = 0; i < 8; ++i) {
        float z = 0.0f;
#pragma unroll
        for (int k = i; k < 8; ++k) z = fmaf(mt[TRI(k) + i], dd[k], z);
        ep = fmaf(z, z, ep);
    }
    float exp_part = -0.5f * ep;

    float det_sum = 0.0f;
#pragma unroll
    for (int i = 0; i < 8; ++i) det_sum = fmaf(ginv[i], ginv[i], det_sum);

    float sumlog0 = __logf(p0 * p0);
    float sumlog1 = __logf(p1 * p1);
    float zeta0   = -0.5f * (8.0f * LOG_2PI_F - sumlog0 + quad0);
    float zeta1   = -0.5f * (8.0f * LOG_2PI_F - sumlog1 + quad1);
    float zeta_n  = -0.5f * (8.0f * LOG_2PI_F + logdetM + qn);
    float scale   = zeta0 + zeta1 - zeta_n;

    float result = __expf(scale + exp_part) / sqrtf(POW8_2PI * det_sum);
    if (bb < (size_t)B) out[bb] = result;
}

extern "C" void kernel_launch(void* const* d_in, const int* in_sizes, int n_in,
                              void* d_out, int out_size, void* d_ws, size_t ws_size,
                              hipStream_t stream) {
    const float* mu0    = (const float*)d_in[0];
    const float* mu1    = (const float*)d_in[1];
    const float* cho0   = (const float*)d_in[2];
    const float* cho1   = (const float*)d_in[3];
    const float* sample = (const float*)d_in[4];
    float* out = (float*)d_out;
    int B = in_sizes[0] / 8;
    int blocks = (B + 63) / 64;
    gms_kernel<<<dim3(blocks), dim3(64), 0, stream>>>(
        mu0, mu1, cho0, cho1, sample, out, B);
}